// Round 1
// 463.519 us; speedup vs baseline: 1.0228x; 1.0228x over previous
//
#include <hip/hip_runtime.h>
#include <math.h>

#define S 8192
#define D 768
#define NA 256
#define NO 256
#define MAXW 40
#define NCAT 13
#define NPOL 3
#define NPROJ (2 + NCAT + NPOL)   // 18 projection columns: [valid0,valid1, cat0..12, pol0..2]

// out layout (flat fp32, reference return order)
#define OFF1 ((size_t)NA * NO * 2 * D)            // asp_ids
#define OFF2 (OFF1 + (size_t)NA * NO)             // opi_ids
#define OFF3 (OFF2 + (size_t)NA * NO)             // cate_out
#define OFF4 (OFF3 + (size_t)NA * NO * NCAT)      // polar_out
#define OFF5 (OFF4 + (size_t)NA * NO * NPOL)      // valid_mask

#define NEGF (-3.402823466e+38f)                  // jnp.finfo(f32).min

typedef float vfloat4 __attribute__((ext_vector_type(4)));

// ---------------------------------------------------------------------------
// Kernel 1: per-span max-pool + projection partials. One block per span.
// Pool loop is compile-time MAXW-unrolled (all loads provably in-bounds:
// head <= S-MAXW-1 so head+39 <= S-2), invalid rows masked to -FLT_MAX via
// cndmask -> full MLP instead of a runtime-width serial loop.
// Projection split across the 4 waves (192-wide d-chunks, f64 LDS reduce)
// to cut the f64 dependent-chain length 4x.
// ---------------------------------------------------------------------------
__global__ __launch_bounds__(256) void span_pool_proj(
    const float* __restrict__ word_rep,
    const int*   __restrict__ aspects,
    const int*   __restrict__ opinions,
    const float* __restrict__ W_valid,   // (1536,2) row-major
    const float* __restrict__ W_cat,     // (1536,13)
    const float* __restrict__ W_pol,     // (1536,3)
    float*  __restrict__ rep_out,
    double* __restrict__ proj_out)
{
    __shared__ float  rep[D];
    __shared__ double part[4][NPROJ];
    const int b = blockIdx.x;     // 0..511
    const int t = threadIdx.x;    // 0..255

    const int* spans = (b < NA) ? aspects : opinions;
    const int  s     = (b < NA) ? b : (b - NA);
    const int  woff  = (b < NA) ? 0 : D;

    const int head  = spans[2 * s];
    const int tail  = spans[2 * s + 1];
    const int width = tail - head;         // 1..40

    if (t < 192) {
        const vfloat4* base = (const vfloat4*)(word_rep + (size_t)head * D) + t;
        vfloat4 m = base[0];
#pragma unroll
        for (int r = 1; r < MAXW; ++r) {
            vfloat4 v = base[(size_t)r * (D / 4)];
            const bool ok = r < width;
            m.x = fmaxf(m.x, ok ? v.x : NEGF);
            m.y = fmaxf(m.y, ok ? v.y : NEGF);
            m.z = fmaxf(m.z, ok ? v.z : NEGF);
            m.w = fmaxf(m.w, ok ? v.w : NEGF);
        }
        ((vfloat4*)rep)[t] = m;
        ((vfloat4*)(rep_out + (size_t)b * D))[t] = m;
    }
    __syncthreads();

    const int w    = t >> 6;   // wave 0..3 -> d-chunk [w*192, w*192+192)
    const int lane = t & 63;
    if (lane < NPROJ) {
        const float* W; int ncol, col;
        if (lane < 2)           { W = W_valid; ncol = 2;    col = lane; }
        else if (lane < 2+NCAT) { W = W_cat;   ncol = NCAT; col = lane - 2; }
        else                    { W = W_pol;   ncol = NPOL; col = lane - 2 - NCAT; }
        const int d0 = w * (D / 4);          // 192-wide chunk
        double a0 = 0.0, a1 = 0.0;           // 2 accumulators break the dep chain
#pragma unroll 8
        for (int d = d0; d < d0 + (D / 4); d += 2) {
            a0 += (double)rep[d]     * (double)W[(size_t)(woff + d)     * ncol + col];
            a1 += (double)rep[d + 1] * (double)W[(size_t)(woff + d + 1) * ncol + col];
        }
        part[w][lane] = a0 + a1;
    }
    __syncthreads();
    if (t < NPROJ)
        proj_out[(size_t)b * NPROJ + t] =
            (part[0][t] + part[1][t]) + (part[2][t] + part[3][t]);
}

// ---------------------------------------------------------------------------
// Kernel 2 (fused pair_small + pair_stream): 1024 blocks x 384 threads.
// Block = (aspect i, 64-pair j-chunk). Aspect float4 held in registers across
// the j-loop; mask recomputed inline from proj (identical f64 arithmetic to
// the previous pair_small -> bit-identical mask). Lanes 192..210 of wave 3
// additionally emit the small outputs (cate/pol/ids/mask). NT stores for the
// 402.6 MB out0 stream protect L2 residency of rep/proj.
// ---------------------------------------------------------------------------
#define JPB 64

__global__ __launch_bounds__(384) void pair_out(
    const vfloat4* __restrict__ rep4,     // 512 rows x 192 float4
    const double*  __restrict__ proj,     // 512 x 18
    const float*   __restrict__ b_valid,
    const float*   __restrict__ b_cat,
    const float*   __restrict__ b_pol,
    float*         __restrict__ out)
{
    const int blk = blockIdx.x;           // 0..1023
    const int i   = blk >> 2;             // aspect 0..255
    const int j0  = (blk & 3) * JPB;      // 0,64,128,192
    const int t   = threadIdx.x;          // 0..383

    const double pa0 = proj[(size_t)i * NPROJ + 0];
    const double pa1 = proj[(size_t)i * NPROJ + 1];
    const double bv0 = (double)b_valid[0];
    const double bv1 = (double)b_valid[1];

    vfloat4 av = (vfloat4)0.f;
    if (t < 192) av = rep4[(size_t)i * 192 + t];

    // small-output role for lanes 192..210: c = 0..12 cate, 13..15 pol,
    // 16 asp_id, 17 opi_id, 18 valid_mask
    const int c = t - 192;
    double pac = 0.0; float bias = 0.0f;
    if (c >= 0 && c < 16) {
        pac  = proj[(size_t)i * NPROJ + 2 + c];
        bias = (c < NCAT) ? b_cat[c] : b_pol[c - NCAT];
    }

    const double* po  = proj + (size_t)(NA + j0) * NPROJ;   // uniform -> s_loads
    vfloat4*      dst = (vfloat4*)out + (size_t)((i << 8) | j0) * 384 + t;

    for (int jj = 0; jj < JPB; ++jj) {
        const int j = j0 + jj;
        const int p = (i << 8) | j;

        const double v0 = pa0 + po[0] + bv0;   // same order as before
        const double v1 = pa1 + po[1] + bv1;
        const bool mask = v0 > v1;             // uniform across the block

        vfloat4 val = (vfloat4)0.f;
        if (mask)
            val = (t < 192) ? av
                            : rep4[(size_t)(NA + j) * 192 + (t - 192)];
        __builtin_nontemporal_store(val, dst);

        if (c >= 0 && c < 16) {
            float v = mask ? (float)(pac + po[2 + c] + (double)bias) : 0.0f;
            if (c < NCAT) out[OFF3 + (size_t)p * NCAT + c] = v;
            else          out[OFF4 + (size_t)p * NPOL + (c - NCAT)] = v;
        } else if (c == 16) {
            out[OFF1 + p] = mask ? (float)i : -1.0f;
        } else if (c == 17) {
            out[OFF2 + p] = mask ? (float)j : -1.0f;
        } else if (c == 18) {
            out[OFF5 + p] = mask ? 1.0f : 0.0f;
        }

        po  += NPROJ;
        dst += 384;
    }
}

extern "C" void kernel_launch(void* const* d_in, const int* in_sizes, int n_in,
                              void* d_out, int out_size, void* d_ws, size_t ws_size,
                              hipStream_t stream)
{
    const float* word_rep = (const float*)d_in[0];   // (8192,768)
    const int*   aspects  = (const int*)  d_in[1];   // (256,2)
    const int*   opinions = (const int*)  d_in[2];   // (256,2)
    const float* W_valid  = (const float*)d_in[3];   // (1536,2)
    const float* b_valid  = (const float*)d_in[4];   // (2,)
    const float* W_cat    = (const float*)d_in[5];   // (1536,13)
    const float* b_cat    = (const float*)d_in[6];   // (13,)
    const float* W_pol    = (const float*)d_in[7];   // (1536,3)
    const float* b_pol    = (const float*)d_in[8];   // (3,)
    float* out = (float*)d_out;

    // ws layout: rep (512*768 f32 = 1.5 MB) | proj (512*18 f64)
    float*  rep  = (float*)d_ws;
    double* proj = (double*)((char*)d_ws + (size_t)(NA + NO) * D * sizeof(float));

    span_pool_proj<<<NA + NO, 256, 0, stream>>>(
        word_rep, aspects, opinions, W_valid, W_cat, W_pol, rep, proj);

    pair_out<<<NA * 4, 384, 0, stream>>>(
        (const vfloat4*)rep, proj, b_valid, b_cat, b_pol, out);
}